// Round 2
// baseline (415.837 us; speedup 1.0000x reference)
//
#include <hip/hip_runtime.h>

#define N_EMB 16384
#define DIM 128
#define NSPLIT 16
#define CPS (N_EMB / NSPLIT) /* 1024 cols per split */
#define BN 128
#define NCT (CPS / BN) /* 8 column tiles per block */
#define NLAB 64

typedef __bf16 bf16x8 __attribute__((ext_vector_type(8)));
typedef float f32x4 __attribute__((ext_vector_type(4)));
typedef unsigned short us8 __attribute__((ext_vector_type(8)));
typedef unsigned int u32;

#define SCALE 2.8853900817779268f /* (1/T)*log2(e), T=0.5 */
#define LN2 0.6931471805599453f

__device__ inline float fast_exp2(float x) {
#if __has_builtin(__builtin_amdgcn_exp2f)
  return __builtin_amdgcn_exp2f(x);
#else
  return exp2f(x);
#endif
}
__device__ inline float fast_log2(float x) {
#if __has_builtin(__builtin_amdgcn_logf)
  return __builtin_amdgcn_logf(x);
#else
  return log2f(x);
#endif
}

// fp32 -> bf16 RNE (finite inputs)
__device__ inline unsigned short f2bf(float f) {
  unsigned int u = __float_as_uint(f);
  u += 0x7fffu + ((u >> 16) & 1u);
  return (unsigned short)(u >> 16);
}

// global->LDS DMA, 16 B per lane. LDS dest = wave-uniform base + lane*16.
__device__ inline void gll16(const unsigned short* g, unsigned short* l) {
  __builtin_amdgcn_global_load_lds(
      (const __attribute__((address_space(1))) u32*)g,
      (__attribute__((address_space(3))) u32*)l, 16, 0, 0);
}

// ---------------------------------------------------------------------------
// Counting sort by label, wave-parallel. Per-wave private histograms (LDS
// atomic conflicts only within one wave, ~16-way), per-label scan across
// waves, then placement with per-wave absolute base counters. Order within a
// label is scrambled -- irrelevant, the loss is permutation-invariant.
// ---------------------------------------------------------------------------
__global__ __launch_bounds__(1024) void perm_kernel(
    const int* __restrict__ labels, int* __restrict__ perm,
    int* __restrict__ gstart) {
  __shared__ int whist[16][NLAB];
  __shared__ int htot[NLAB];
  const int tid = threadIdx.x;
  const int w = tid >> 6, lane = tid & 63;
  whist[w][lane] = 0; // 1024 threads == 16x64 entries
  __syncthreads();
  const int base_i = w * 1024;
  int mylab[16];
#pragma unroll
  for (int k = 0; k < 16; ++k) {
    int lab = labels[base_i + k * 64 + lane];
    mylab[k] = lab;
    atomicAdd(&whist[w][lab], 1);
  }
  __syncthreads();
  if (tid < NLAB) { // per-label exclusive scan over waves + total
    int s = 0;
#pragma unroll
    for (int ww = 0; ww < 16; ++ww) {
      int t = whist[ww][tid];
      whist[ww][tid] = s;
      s += t;
    }
    htot[tid] = s;
  }
  __syncthreads();
  if (tid == 0) { // exclusive prefix over labels
    int s = 0;
    for (int l = 0; l < NLAB; ++l) {
      int t = htot[l];
      gstart[l] = s;
      htot[l] = s;
      s += t;
    }
    gstart[NLAB] = s;
  }
  __syncthreads();
  whist[w][lane] += htot[lane]; // absolute base per (wave,label)
  __syncthreads();
#pragma unroll
  for (int k = 0; k < 16; ++k) {
    int lab = mylab[k];
    int pos = atomicAdd(&whist[w][lab], 1);
    perm[pos] = base_i + k * 64 + lane;
  }
}

// ---------------------------------------------------------------------------
// Gather (permuted) + fp32->bf16 convert into fragment-linear layout.
// Granule G of 128-row tile t: row = tc*16+col16, dims ks*32+quad*8..+7,
// stored at element t*16384 + G*8. Fragment (T global 16-row tile, ks) is at
// (T>>3)*16384 + ((T&7)*4+ks)*512 + lane*8 -- lane-contiguous 16B/lane.
// ---------------------------------------------------------------------------
__global__ __launch_bounds__(256) void preconv(
    const float* __restrict__ emb, const int* __restrict__ perm,
    unsigned short* __restrict__ eraw) {
  const int tid = threadIdx.x;
  const int tile = blockIdx.x >> 2;
  const int part = blockIdx.x & 3;
  const size_t base = (size_t)tile * (128 * DIM);
#pragma unroll
  for (int i = 0; i < 2; ++i) {
    int G = part * 512 + i * 256 + tid;
    int col16 = G & 15;
    int qd = (G >> 4) & 3;
    int ks = (G >> 6) & 3;
    int tc = G >> 8;
    int srow = perm[tile * 128 + tc * 16 + col16];
    const float* p = emb + (size_t)srow * DIM + ks * 32 + qd * 8;
    float4 a = *reinterpret_cast<const float4*>(p);
    float4 b = *reinterpret_cast<const float4*>(p + 4);
    us8 g;
    g[0] = f2bf(a.x); g[1] = f2bf(a.y); g[2] = f2bf(a.z); g[3] = f2bf(a.w);
    g[4] = f2bf(b.x); g[5] = f2bf(b.y); g[6] = f2bf(b.z); g[7] = f2bf(b.w);
    *reinterpret_cast<us8*>(eraw + base + (size_t)G * 8) = g;
  }
}

// Load one A fragment from raw bf16 and pre-scale by SCALE (bitwise identical
// to a precomputed scaled buffer: bf16 -> f32 -> *SCALE -> RNE bf16).
__device__ inline bf16x8 load_scaled(const unsigned short* p) {
  us8 v = *reinterpret_cast<const us8*>(p);
  us8 s;
#pragma unroll
  for (int j = 0; j < 8; ++j)
    s[j] = f2bf(__uint_as_float((u32)v[j] << 16) * SCALE);
  return *reinterpret_cast<bf16x8*>(&s);
}

// ---------------------------------------------------------------------------
// Main N^2 kernel: all_sum ONLY (diag included; subtracted in finalize).
// 4 waves/block, each wave owns 64 rows (256 rows/block). Grid (64, NSPLIT=16)
// = 1024 blocks -> 4 blocks/CU (LDS 128 KB of 160), 16 waves/CU for
// MFMA||VALU||barrier-drain overlap across blocks. Epilogue = exp2 + add.
// ---------------------------------------------------------------------------
__global__ __launch_bounds__(256, 4) void cl_all(
    const unsigned short* __restrict__ eraw, float* __restrict__ ws_all) {
  __shared__ unsigned short lds[BN * DIM]; // 32 KB B tile
  const int tid = threadIdx.x;
  const int lane = tid & 63;
  const int w = tid >> 6; // wave 0..3, owns rows [r0+w*64, r0+w*64+64)
  const int col16 = lane & 15;
  const int quad = lane >> 4;
  const int r0 = blockIdx.x * 256;
  const int cs = blockIdx.y;

  // A-frag: lane holds A[m=lane&15][k=quad*8+j] for 16-row tile T, scaled.
  bf16x8 afrag[4][4];
#pragma unroll
  for (int tr = 0; tr < 4; ++tr) {
    const int T = (r0 >> 4) + w * 4 + tr;
    const unsigned short* p = eraw + (size_t)(T >> 3) * (128 * DIM) +
                              ((T & 7) * 4) * 512 + lane * 8;
#pragma unroll
    for (int ks = 0; ks < 4; ++ks) afrag[tr][ks] = load_scaled(p + ks * 512);
  }

  float all_p[16];
#pragma unroll
  for (int t = 0; t < 16; ++t) all_p[t] = 0.f;

  for (int ct = 0; ct < NCT; ++ct) {
    const int c0 = cs * CPS + ct * BN;
    __syncthreads(); // prior compute done before overwrite
    {
      const unsigned short* g = eraw + (size_t)c0 * DIM;
#pragma unroll
      for (int i = 0; i < 8; ++i) {
        int chunk = i * 4 + w;
        gll16(g + chunk * 512 + lane * 8, lds + chunk * 512);
      }
    }
    __syncthreads(); // vmcnt(0) drained -> B tile visible

#pragma unroll
    for (int tc = 0; tc < 8; ++tc) {
      bf16x8 bfr[4];
#pragma unroll
      for (int ks = 0; ks < 4; ++ks)
        bfr[ks] = *reinterpret_cast<const bf16x8*>(lds + (tc * 4 + ks) * 512 +
                                                   lane * 8);
#pragma unroll
      for (int tr = 0; tr < 4; ++tr) {
        f32x4 acc = {0.f, 0.f, 0.f, 0.f};
#pragma unroll
        for (int ks = 0; ks < 4; ++ks)
          acc = __builtin_amdgcn_mfma_f32_16x16x32_bf16(afrag[tr][ks], bfr[ks],
                                                        acc, 0, 0, 0);
        // C/D layout (verified): col = lane&15, row = quad*4 + r
#pragma unroll
        for (int r = 0; r < 4; ++r) all_p[tr * 4 + r] += fast_exp2(acc[r]);
      }
    }
  }

#pragma unroll
  for (int t = 0; t < 16; ++t) {
    float a = all_p[t];
#pragma unroll
    for (int m = 8; m >= 1; m >>= 1) a += __shfl_xor(a, m, 64);
    if (col16 == 0) {
      int row_g = r0 + w * 64 + (t >> 2) * 16 + quad * 4 + (t & 3);
      ws_all[cs * N_EMB + row_g] = a;
    }
  }
}

// ---------------------------------------------------------------------------
// Block-diagonal positives: one (label, chunk) per block. pos_sum (diag
// excluded) per row, plus ws_diag[i] = exp2(acc_ii) with bitwise-identical
// fragments/MFMA order to cl_all, so finalize subtracts the exact diag term.
// ---------------------------------------------------------------------------
__global__ __launch_bounds__(256) void cl_pos(
    const unsigned short* __restrict__ eraw, const int* __restrict__ gstart,
    float* __restrict__ ws_pos, float* __restrict__ ws_diag) {
  const int l = blockIdx.x;
  const int chunk = blockIdx.y;
  const int gs = gstart[l], ge = gstart[l + 1];
  const int tid = threadIdx.x;
  const int lane = tid & 63;
  const int w = tid >> 6;
  const int col16 = lane & 15;
  const int quad = lane >> 4;
  const int t0 = gs >> 4;        // first 16-row tile touching group
  const int t1 = (ge + 15) >> 4; // exclusive end

  for (int ta = t0 + chunk * 4 + w; ta < t1; ta += 16) {
    bf16x8 af[4];
    const unsigned short* pa = eraw + (size_t)(ta >> 3) * (128 * DIM) +
                               ((ta & 7) * 4) * 512 + lane * 8;
#pragma unroll
    for (int ks = 0; ks < 4; ++ks) af[ks] = load_scaled(pa + ks * 512);
    const int grow = ta * 16 + quad * 4; // this lane's 4 rows: grow+r
    float posr[4] = {0.f, 0.f, 0.f, 0.f};

    for (int tb = t0; tb < t1; ++tb) {
      bf16x8 bfr[4];
      const unsigned short* pb = eraw + (size_t)(tb >> 3) * (128 * DIM) +
                                 ((tb & 7) * 4) * 512 + lane * 8;
#pragma unroll
      for (int ks = 0; ks < 4; ++ks)
        bfr[ks] = *reinterpret_cast<const bf16x8*>(pb + ks * 512);
      f32x4 acc = {0.f, 0.f, 0.f, 0.f};
#pragma unroll
      for (int ks = 0; ks < 4; ++ks)
        acc = __builtin_amdgcn_mfma_f32_16x16x32_bf16(af[ks], bfr[ks], acc, 0,
                                                      0, 0);
      const int gcol = tb * 16 + col16;
      const bool colin = (gcol >= gs) && (gcol < ge);
#pragma unroll
      for (int r = 0; r < 4; ++r) {
        float e = fast_exp2(acc[r]);
        const int gr = grow + r;
        if (gcol == gr) {
          if (colin) ws_diag[gr] = e; // exactly one writer per row
        } else if (colin) {
          posr[r] += e;
        }
      }
    }

#pragma unroll
    for (int r = 0; r < 4; ++r) {
      float p = posr[r];
#pragma unroll
      for (int m = 8; m >= 1; m >>= 1) p += __shfl_xor(p, m, 64);
      const int gr = grow + r;
      if (col16 == 0 && gr >= gs && gr < ge) ws_pos[gr] = p;
    }
  }
}

// ---------------------------------------------------------------------------
// Finalize: 64-block partial reduce, then one wave combines.
// ---------------------------------------------------------------------------
__global__ __launch_bounds__(256) void fin1(
    const float* __restrict__ ws_all, const float* __restrict__ ws_pos,
    const float* __restrict__ ws_diag, float* __restrict__ part_tot,
    int* __restrict__ part_cnt) {
  __shared__ float s_t[256];
  __shared__ int s_c[256];
  const int tid = threadIdx.x;
  const int row = blockIdx.x * 256 + tid;
  float a = 0.f;
#pragma unroll
  for (int s = 0; s < NSPLIT; ++s) a += ws_all[s * N_EMB + row];
  a -= ws_diag[row];
  const float p = ws_pos[row];
  float t = 0.f;
  int c = 0;
  if (p > 0.f) {
    t = fast_log2(a) - fast_log2(p);
    c = 1;
  }
  s_t[tid] = t;
  s_c[tid] = c;
  __syncthreads();
  for (int s = 128; s > 0; s >>= 1) {
    if (tid < s) {
      s_t[tid] += s_t[tid + s];
      s_c[tid] += s_c[tid + s];
    }
    __syncthreads();
  }
  if (tid == 0) {
    part_tot[blockIdx.x] = s_t[0];
    part_cnt[blockIdx.x] = s_c[0];
  }
}

__global__ __launch_bounds__(64) void fin2(const float* __restrict__ part_tot,
                                           const int* __restrict__ part_cnt,
                                           float* __restrict__ out) {
  const int tid = threadIdx.x;
  float t = part_tot[tid];
  int c = part_cnt[tid];
#pragma unroll
  for (int m = 32; m >= 1; m >>= 1) {
    t += __shfl_xor(t, m, 64);
    c += __shfl_xor(c, m, 64);
  }
  if (tid == 0) out[0] = (c > 0) ? (t * LN2 / (float)c) : 0.f;
}

extern "C" void kernel_launch(void* const* d_in, const int* in_sizes, int n_in,
                              void* d_out, int out_size, void* d_ws,
                              size_t ws_size, hipStream_t stream) {
  const float* emb = (const float*)d_in[0];
  const int* labels = (const int*)d_in[1];

  unsigned short* eraw = (unsigned short*)d_ws;       // 4 MB bf16 frag-linear
  float* ws_all = (float*)(eraw + (size_t)N_EMB * DIM); // [NSPLIT][N] 1 MB
  float* ws_pos = ws_all + NSPLIT * N_EMB;            // [N] 64 KB
  float* ws_diag = ws_pos + N_EMB;                    // [N] 64 KB
  float* part_tot = ws_diag + N_EMB;                  // [64]
  int* part_cnt = (int*)(part_tot + 64);              // [64]
  int* perm = part_cnt + 64;                          // [N] 64 KB
  int* gstart = perm + N_EMB;                         // [65]

  perm_kernel<<<1, 1024, 0, stream>>>(labels, perm, gstart);
  preconv<<<512, 256, 0, stream>>>(emb, perm, eraw);
  cl_all<<<dim3(N_EMB / 256, NSPLIT), 256, 0, stream>>>(eraw, ws_all);
  cl_pos<<<dim3(NLAB, 4), 256, 0, stream>>>(eraw, gstart, ws_pos, ws_diag);
  fin1<<<N_EMB / 256, 256, 0, stream>>>(ws_all, ws_pos, ws_diag, part_tot,
                                        part_cnt);
  fin2<<<1, 64, 0, stream>>>(part_tot, part_cnt, (float*)d_out);
}

// Round 3
// 166.114 us; speedup vs baseline: 2.5033x; 2.5033x over previous
//
#include <hip/hip_runtime.h>

#define N_EMB 16384
#define DIM 128
#define NSPLIT 16
#define CPS (N_EMB / NSPLIT) /* 1024 cols per split */
#define BN 128
#define NCT (CPS / BN) /* 8 column tiles per block */
#define NLAB 64

typedef __bf16 bf16x8 __attribute__((ext_vector_type(8)));
typedef float f32x4 __attribute__((ext_vector_type(4)));
typedef unsigned short us8 __attribute__((ext_vector_type(8)));
typedef unsigned int u32;

#define SCALE 2.8853900817779268f /* (1/T)*log2(e), T=0.5 */
#define LN2 0.6931471805599453f

__device__ inline float fast_exp2(float x) {
#if __has_builtin(__builtin_amdgcn_exp2f)
  return __builtin_amdgcn_exp2f(x);
#else
  return exp2f(x);
#endif
}
__device__ inline float fast_log2(float x) {
#if __has_builtin(__builtin_amdgcn_logf)
  return __builtin_amdgcn_logf(x);
#else
  return log2f(x);
#endif
}

// fp32 -> bf16 RNE (finite inputs)
__device__ inline unsigned short f2bf(float f) {
  unsigned int u = __float_as_uint(f);
  u += 0x7fffu + ((u >> 16) & 1u);
  return (unsigned short)(u >> 16);
}

// global->LDS DMA, 16 B per lane. LDS dest = wave-uniform base + lane*16.
__device__ inline void gll16(const unsigned short* g, unsigned short* l) {
  __builtin_amdgcn_global_load_lds(
      (const __attribute__((address_space(1))) u32*)g,
      (__attribute__((address_space(3))) u32*)l, 16, 0, 0);
}

// ---------------------------------------------------------------------------
// Counting sort by label, wave-parallel. Per-wave private histograms (LDS
// atomic conflicts only within one wave), per-label scan across waves, then
// placement with per-wave absolute base counters. Order within a label is
// scrambled -- irrelevant, the loss is permutation-invariant.
// ---------------------------------------------------------------------------
__global__ __launch_bounds__(1024) void perm_kernel(
    const int* __restrict__ labels, int* __restrict__ perm,
    int* __restrict__ gstart) {
  __shared__ int whist[16][NLAB];
  __shared__ int htot[NLAB];
  const int tid = threadIdx.x;
  const int w = tid >> 6, lane = tid & 63;
  whist[w][lane] = 0; // 1024 threads == 16x64 entries
  __syncthreads();
  const int base_i = w * 1024;
  int mylab[16];
#pragma unroll
  for (int k = 0; k < 16; ++k) {
    int lab = labels[base_i + k * 64 + lane];
    mylab[k] = lab;
    atomicAdd(&whist[w][lab], 1);
  }
  __syncthreads();
  if (tid < NLAB) { // per-label exclusive scan over waves + total
    int s = 0;
#pragma unroll
    for (int ww = 0; ww < 16; ++ww) {
      int t = whist[ww][tid];
      whist[ww][tid] = s;
      s += t;
    }
    htot[tid] = s;
  }
  __syncthreads();
  if (tid == 0) { // exclusive prefix over labels
    int s = 0;
    for (int l = 0; l < NLAB; ++l) {
      int t = htot[l];
      gstart[l] = s;
      htot[l] = s;
      s += t;
    }
    gstart[NLAB] = s;
  }
  __syncthreads();
  whist[w][lane] += htot[lane]; // absolute base per (wave,label)
  __syncthreads();
#pragma unroll
  for (int k = 0; k < 16; ++k) {
    int lab = mylab[k];
    int pos = atomicAdd(&whist[w][lab], 1);
    perm[pos] = base_i + k * 64 + lane;
  }
}

// ---------------------------------------------------------------------------
// Gather (permuted) + fp32->bf16 convert into fragment-linear layout.
// Granule G of 128-row tile t: row = tc*16+col16, dims ks*32+quad*8..+7,
// stored at element t*16384 + G*8. Fragment (T global 16-row tile, ks) is at
// (T>>3)*16384 + ((T&7)*4+ks)*512 + lane*8 -- lane-contiguous 16B/lane.
// ---------------------------------------------------------------------------
__global__ __launch_bounds__(256) void preconv(
    const float* __restrict__ emb, const int* __restrict__ perm,
    unsigned short* __restrict__ eraw) {
  const int tid = threadIdx.x;
  const int tile = blockIdx.x >> 2;
  const int part = blockIdx.x & 3;
  const size_t base = (size_t)tile * (128 * DIM);
#pragma unroll
  for (int i = 0; i < 2; ++i) {
    int G = part * 512 + i * 256 + tid;
    int col16 = G & 15;
    int qd = (G >> 4) & 3;
    int ks = (G >> 6) & 3;
    int tc = G >> 8;
    int srow = perm[tile * 128 + tc * 16 + col16];
    const float* p = emb + (size_t)srow * DIM + ks * 32 + qd * 8;
    float4 a = *reinterpret_cast<const float4*>(p);
    float4 b = *reinterpret_cast<const float4*>(p + 4);
    us8 g;
    g[0] = f2bf(a.x); g[1] = f2bf(a.y); g[2] = f2bf(a.z); g[3] = f2bf(a.w);
    g[4] = f2bf(b.x); g[5] = f2bf(b.y); g[6] = f2bf(b.z); g[7] = f2bf(b.w);
    *reinterpret_cast<us8*>(eraw + base + (size_t)G * 8) = g;
  }
}

// Load one A fragment from raw bf16 and pre-scale by SCALE (bitwise identical
// to a precomputed scaled buffer: bf16 -> f32 -> *SCALE -> RNE bf16).
__device__ inline bf16x8 load_scaled(const unsigned short* p) {
  us8 v = *reinterpret_cast<const us8*>(p);
  us8 s;
#pragma unroll
  for (int j = 0; j < 8; ++j)
    s[j] = f2bf(__uint_as_float((u32)v[j] << 16) * SCALE);
  return *reinterpret_cast<bf16x8*>(&s);
}

// ---------------------------------------------------------------------------
// Main N^2 kernel: all_sum ONLY (diag included; subtracted in finalize).
// 4 waves/block, each wave owns 64 rows (256 rows/block). Grid (64, NSPLIT=16)
// = 1024 blocks. NO min-waves clamp: (256,4) empirically caps the allocator
// at 64 VGPRs and spills afrag to scratch (round-2 post-mortem: 1.4 GB/dispatch
// scratch traffic). Demand-driven allocation (~130-170 VGPR) -> 3 waves/EU,
// 12 waves/CU, zero spill. LDS = one 32 KB B tile shared by 4 waves.
// ---------------------------------------------------------------------------
__global__ __launch_bounds__(256) void cl_all(
    const unsigned short* __restrict__ eraw, float* __restrict__ ws_all) {
  __shared__ unsigned short lds[BN * DIM]; // 32 KB B tile
  const int tid = threadIdx.x;
  const int lane = tid & 63;
  const int w = tid >> 6; // wave 0..3, owns rows [r0+w*64, r0+w*64+64)
  const int col16 = lane & 15;
  const int quad = lane >> 4;
  const int r0 = blockIdx.x * 256;
  const int cs = blockIdx.y;

  // A-frag: lane holds A[m=lane&15][k=quad*8+j] for 16-row tile T, scaled.
  bf16x8 afrag[4][4];
#pragma unroll
  for (int tr = 0; tr < 4; ++tr) {
    const int T = (r0 >> 4) + w * 4 + tr;
    const unsigned short* p = eraw + (size_t)(T >> 3) * (128 * DIM) +
                              ((T & 7) * 4) * 512 + lane * 8;
#pragma unroll
    for (int ks = 0; ks < 4; ++ks) afrag[tr][ks] = load_scaled(p + ks * 512);
  }

  float all_p[16];
#pragma unroll
  for (int t = 0; t < 16; ++t) all_p[t] = 0.f;

  for (int ct = 0; ct < NCT; ++ct) {
    const int c0 = cs * CPS + ct * BN;
    __syncthreads(); // prior compute done before overwrite
    {
      const unsigned short* g = eraw + (size_t)c0 * DIM;
#pragma unroll
      for (int i = 0; i < 8; ++i) {
        int chunk = i * 4 + w;
        gll16(g + chunk * 512 + lane * 8, lds + chunk * 512);
      }
    }
    __syncthreads(); // vmcnt(0) drained -> B tile visible

#pragma unroll
    for (int tc = 0; tc < 8; ++tc) {
      bf16x8 bfr[4];
#pragma unroll
      for (int ks = 0; ks < 4; ++ks)
        bfr[ks] = *reinterpret_cast<const bf16x8*>(lds + (tc * 4 + ks) * 512 +
                                                   lane * 8);
#pragma unroll
      for (int tr = 0; tr < 4; ++tr) {
        f32x4 acc = {0.f, 0.f, 0.f, 0.f};
#pragma unroll
        for (int ks = 0; ks < 4; ++ks)
          acc = __builtin_amdgcn_mfma_f32_16x16x32_bf16(afrag[tr][ks], bfr[ks],
                                                        acc, 0, 0, 0);
        // C/D layout (verified): col = lane&15, row = quad*4 + r
#pragma unroll
        for (int r = 0; r < 4; ++r) all_p[tr * 4 + r] += fast_exp2(acc[r]);
      }
    }
  }

#pragma unroll
  for (int t = 0; t < 16; ++t) {
    float a = all_p[t];
#pragma unroll
    for (int m = 8; m >= 1; m >>= 1) a += __shfl_xor(a, m, 64);
    if (col16 == 0) {
      int row_g = r0 + w * 64 + (t >> 2) * 16 + quad * 4 + (t & 3);
      ws_all[cs * N_EMB + row_g] = a;
    }
  }
}

// ---------------------------------------------------------------------------
// Block-diagonal positives: one (label, chunk) per block. pos_sum (diag
// excluded) per row, plus ws_diag[i] = exp2(acc_ii) with bitwise-identical
// fragments/MFMA order to cl_all, so finalize subtracts the exact diag term.
// ---------------------------------------------------------------------------
__global__ __launch_bounds__(256) void cl_pos(
    const unsigned short* __restrict__ eraw, const int* __restrict__ gstart,
    float* __restrict__ ws_pos, float* __restrict__ ws_diag) {
  const int l = blockIdx.x;
  const int chunk = blockIdx.y;
  const int gs = gstart[l], ge = gstart[l + 1];
  const int tid = threadIdx.x;
  const int lane = tid & 63;
  const int w = tid >> 6;
  const int col16 = lane & 15;
  const int quad = lane >> 4;
  const int t0 = gs >> 4;        // first 16-row tile touching group
  const int t1 = (ge + 15) >> 4; // exclusive end

  for (int ta = t0 + chunk * 4 + w; ta < t1; ta += 16) {
    bf16x8 af[4];
    const unsigned short* pa = eraw + (size_t)(ta >> 3) * (128 * DIM) +
                               ((ta & 7) * 4) * 512 + lane * 8;
#pragma unroll
    for (int ks = 0; ks < 4; ++ks) af[ks] = load_scaled(pa + ks * 512);
    const int grow = ta * 16 + quad * 4; // this lane's 4 rows: grow+r
    float posr[4] = {0.f, 0.f, 0.f, 0.f};

    for (int tb = t0; tb < t1; ++tb) {
      bf16x8 bfr[4];
      const unsigned short* pb = eraw + (size_t)(tb >> 3) * (128 * DIM) +
                                 ((tb & 7) * 4) * 512 + lane * 8;
#pragma unroll
      for (int ks = 0; ks < 4; ++ks)
        bfr[ks] = *reinterpret_cast<const bf16x8*>(pb + ks * 512);
      f32x4 acc = {0.f, 0.f, 0.f, 0.f};
#pragma unroll
      for (int ks = 0; ks < 4; ++ks)
        acc = __builtin_amdgcn_mfma_f32_16x16x32_bf16(af[ks], bfr[ks], acc, 0,
                                                      0, 0);
      const int gcol = tb * 16 + col16;
      const bool colin = (gcol >= gs) && (gcol < ge);
#pragma unroll
      for (int r = 0; r < 4; ++r) {
        float e = fast_exp2(acc[r]);
        const int gr = grow + r;
        if (gcol == gr) {
          if (colin) ws_diag[gr] = e; // exactly one writer per row
        } else if (colin) {
          posr[r] += e;
        }
      }
    }

#pragma unroll
    for (int r = 0; r < 4; ++r) {
      float p = posr[r];
#pragma unroll
      for (int m = 8; m >= 1; m >>= 1) p += __shfl_xor(p, m, 64);
      const int gr = grow + r;
      if (col16 == 0 && gr >= gs && gr < ge) ws_pos[gr] = p;
    }
  }
}

// ---------------------------------------------------------------------------
// Finalize: 64-block partial reduce, then one wave combines.
// ---------------------------------------------------------------------------
__global__ __launch_bounds__(256) void fin1(
    const float* __restrict__ ws_all, const float* __restrict__ ws_pos,
    const float* __restrict__ ws_diag, float* __restrict__ part_tot,
    int* __restrict__ part_cnt) {
  __shared__ float s_t[256];
  __shared__ int s_c[256];
  const int tid = threadIdx.x;
  const int row = blockIdx.x * 256 + tid;
  float a = 0.f;
#pragma unroll
  for (int s = 0; s < NSPLIT; ++s) a += ws_all[s * N_EMB + row];
  a -= ws_diag[row];
  const float p = ws_pos[row];
  float t = 0.f;
  int c = 0;
  if (p > 0.f) {
    t = fast_log2(a) - fast_log2(p);
    c = 1;
  }
  s_t[tid] = t;
  s_c[tid] = c;
  __syncthreads();
  for (int s = 128; s > 0; s >>= 1) {
    if (tid < s) {
      s_t[tid] += s_t[tid + s];
      s_c[tid] += s_c[tid + s];
    }
    __syncthreads();
  }
  if (tid == 0) {
    part_tot[blockIdx.x] = s_t[0];
    part_cnt[blockIdx.x] = s_c[0];
  }
}

__global__ __launch_bounds__(64) void fin2(const float* __restrict__ part_tot,
                                           const int* __restrict__ part_cnt,
                                           float* __restrict__ out) {
  const int tid = threadIdx.x;
  float t = part_tot[tid];
  int c = part_cnt[tid];
#pragma unroll
  for (int m = 32; m >= 1; m >>= 1) {
    t += __shfl_xor(t, m, 64);
    c += __shfl_xor(c, m, 64);
  }
  if (tid == 0) out[0] = (c > 0) ? (t * LN2 / (float)c) : 0.f;
}

extern "C" void kernel_launch(void* const* d_in, const int* in_sizes, int n_in,
                              void* d_out, int out_size, void* d_ws,
                              size_t ws_size, hipStream_t stream) {
  const float* emb = (const float*)d_in[0];
  const int* labels = (const int*)d_in[1];

  unsigned short* eraw = (unsigned short*)d_ws;         // 4 MB bf16 frag-linear
  float* ws_all = (float*)(eraw + (size_t)N_EMB * DIM); // [NSPLIT][N] 1 MB
  float* ws_pos = ws_all + NSPLIT * N_EMB;              // [N] 64 KB
  float* ws_diag = ws_pos + N_EMB;                      // [N] 64 KB
  float* part_tot = ws_diag + N_EMB;                    // [64]
  int* part_cnt = (int*)(part_tot + 64);                // [64]
  int* perm = part_cnt + 64;                            // [N] 64 KB
  int* gstart = perm + N_EMB;                           // [65]

  perm_kernel<<<1, 1024, 0, stream>>>(labels, perm, gstart);
  preconv<<<512, 256, 0, stream>>>(emb, perm, eraw);
  cl_all<<<dim3(N_EMB / 256, NSPLIT), 256, 0, stream>>>(eraw, ws_all);
  cl_pos<<<dim3(NLAB, 4), 256, 0, stream>>>(eraw, gstart, ws_pos, ws_diag);
  fin1<<<N_EMB / 256, 256, 0, stream>>>(ws_all, ws_pos, ws_diag, part_tot,
                                        part_cnt);
  fin2<<<1, 64, 0, stream>>>(part_tot, part_cnt, (float*)d_out);
}

// Round 4
// 155.888 us; speedup vs baseline: 2.6675x; 1.0656x over previous
//
#include <hip/hip_runtime.h>

#define N_EMB 16384
#define DIM 128
#define NSPLIT 16
#define CPS (N_EMB / NSPLIT) /* 1024 cols per split */
#define BN 64
#define NCT (CPS / BN) /* 16 column tiles per block */
#define NLAB 64
#define POSY 4 /* extra grid.y slices running the pos path */

typedef __bf16 bf16x8 __attribute__((ext_vector_type(8)));
typedef float f32x4 __attribute__((ext_vector_type(4)));
typedef unsigned short us8 __attribute__((ext_vector_type(8)));
typedef unsigned int u32;

#define SCALE 2.8853900817779268f /* (1/T)*log2(e), T=0.5 */
#define LN2 0.6931471805599453f

__device__ inline float fast_exp2(float x) {
#if __has_builtin(__builtin_amdgcn_exp2f)
  return __builtin_amdgcn_exp2f(x);
#else
  return exp2f(x);
#endif
}
__device__ inline float fast_log2(float x) {
#if __has_builtin(__builtin_amdgcn_logf)
  return __builtin_amdgcn_logf(x);
#else
  return log2f(x);
#endif
}

// fp32 -> bf16 RNE (finite inputs)
__device__ inline unsigned short f2bf(float f) {
  unsigned int u = __float_as_uint(f);
  u += 0x7fffu + ((u >> 16) & 1u);
  return (unsigned short)(u >> 16);
}

// global->LDS DMA, 16 B per lane. LDS dest = wave-uniform base + lane*16.
__device__ inline void gll16(const unsigned short* g, unsigned short* l) {
  __builtin_amdgcn_global_load_lds(
      (const __attribute__((address_space(1))) u32*)g,
      (__attribute__((address_space(3))) u32*)l, 16, 0, 0);
}

// ---------------------------------------------------------------------------
// Counting sort by label, wave-parallel (round-3 version, verified).
// ---------------------------------------------------------------------------
__global__ __launch_bounds__(1024) void perm_kernel(
    const int* __restrict__ labels, int* __restrict__ perm,
    int* __restrict__ gstart) {
  __shared__ int whist[16][NLAB];
  __shared__ int htot[NLAB];
  const int tid = threadIdx.x;
  const int w = tid >> 6, lane = tid & 63;
  whist[w][lane] = 0;
  __syncthreads();
  const int base_i = w * 1024;
  int mylab[16];
#pragma unroll
  for (int k = 0; k < 16; ++k) {
    int lab = labels[base_i + k * 64 + lane];
    mylab[k] = lab;
    atomicAdd(&whist[w][lab], 1);
  }
  __syncthreads();
  if (tid < NLAB) {
    int s = 0;
#pragma unroll
    for (int ww = 0; ww < 16; ++ww) {
      int t = whist[ww][tid];
      whist[ww][tid] = s;
      s += t;
    }
    htot[tid] = s;
  }
  __syncthreads();
  if (tid == 0) {
    int s = 0;
    for (int l = 0; l < NLAB; ++l) {
      int t = htot[l];
      gstart[l] = s;
      htot[l] = s;
      s += t;
    }
    gstart[NLAB] = s;
  }
  __syncthreads();
  whist[w][lane] += htot[lane];
  __syncthreads();
#pragma unroll
  for (int k = 0; k < 16; ++k) {
    int lab = mylab[k];
    int pos = atomicAdd(&whist[w][lab], 1);
    perm[pos] = base_i + k * 64 + lane;
  }
}

// ---------------------------------------------------------------------------
// Gather (permuted) + fp32->bf16 convert into fragment-linear layout.
// Granule G of 128-row tile t: row = tc*16+col16, dims ks*32+quad*8..+7,
// stored at element t*16384 + G*8.
// ---------------------------------------------------------------------------
__global__ __launch_bounds__(256) void preconv(
    const float* __restrict__ emb, const int* __restrict__ perm,
    unsigned short* __restrict__ eraw) {
  const int tid = threadIdx.x;
  const int tile = blockIdx.x >> 2;
  const int part = blockIdx.x & 3;
  const size_t base = (size_t)tile * (128 * DIM);
#pragma unroll
  for (int i = 0; i < 2; ++i) {
    int G = part * 512 + i * 256 + tid;
    int col16 = G & 15;
    int qd = (G >> 4) & 3;
    int ks = (G >> 6) & 3;
    int tc = G >> 8;
    int srow = perm[tile * 128 + tc * 16 + col16];
    const float* p = emb + (size_t)srow * DIM + ks * 32 + qd * 8;
    float4 a = *reinterpret_cast<const float4*>(p);
    float4 b = *reinterpret_cast<const float4*>(p + 4);
    us8 g;
    g[0] = f2bf(a.x); g[1] = f2bf(a.y); g[2] = f2bf(a.z); g[3] = f2bf(a.w);
    g[4] = f2bf(b.x); g[5] = f2bf(b.y); g[6] = f2bf(b.z); g[7] = f2bf(b.w);
    *reinterpret_cast<us8*>(eraw + base + (size_t)G * 8) = g;
  }
}

// Load one A fragment from raw bf16 and pre-scale by SCALE.
__device__ inline bf16x8 load_scaled(const unsigned short* p) {
  us8 v = *reinterpret_cast<const us8*>(p);
  us8 s;
#pragma unroll
  for (int j = 0; j < 8; ++j)
    s[j] = f2bf(__uint_as_float((u32)v[j] << 16) * SCALE);
  return *reinterpret_cast<bf16x8*>(&s);
}

// ---------------------------------------------------------------------------
// Fused main kernel. grid (128, NSPLIT+POSY), 128 threads (2 waves).
//  cs < NSPLIT : all-path. Wave owns 64 rows; B tiles (64 cols) double-
//    buffered in LDS via T3 2-phase: issue DMA of tile t+1, compute tile t,
//    then ONE vmcnt(0)+barrier -- staging latency hides under 64 MFMA+exp2.
//  cs >= NSPLIT: pos-path (block-diagonal positives + exact diag terms),
//    dispatched last -> fills the tail of the all-path blocks.
// No min-waves clamp (round-2 post-mortem: (256,4) forced 64 VGPR + spills).
// ---------------------------------------------------------------------------
__global__ __launch_bounds__(128) void cl_fused(
    const unsigned short* __restrict__ eraw, const int* __restrict__ gstart,
    float* __restrict__ ws_all, float* __restrict__ ws_pos,
    float* __restrict__ ws_diag) {
  __shared__ unsigned short lds0[BN * DIM]; // 16 KB
  __shared__ unsigned short lds1[BN * DIM]; // 16 KB
  const int tid = threadIdx.x;
  const int lane = tid & 63;
  const int w = tid >> 6; // wave 0..1
  const int col16 = lane & 15;
  const int quad = lane >> 4;
  const int cs = blockIdx.y;

  if (cs < NSPLIT) {
    // ------------------------- all-path -------------------------
    const int r0 = blockIdx.x * 128;

    bf16x8 afrag[4][4];
#pragma unroll
    for (int tr = 0; tr < 4; ++tr) {
      const int T = (r0 >> 4) + w * 4 + tr;
      const unsigned short* p = eraw + (size_t)(T >> 3) * (128 * DIM) +
                                ((T & 7) * 4) * 512 + lane * 8;
#pragma unroll
      for (int ks = 0; ks < 4; ++ks) afrag[tr][ks] = load_scaled(p + ks * 512);
    }

    float all_p[16];
#pragma unroll
    for (int t = 0; t < 16; ++t) all_p[t] = 0.f;

    // stage a 64-col tile (16 KB, contiguous half of a 128-row frag tile)
    auto stage = [&](unsigned short* dst, int c0) {
      const unsigned short* g = eraw + (size_t)(c0 >> 7) * (128 * DIM) +
                                (size_t)((c0 >> 6) & 1) * 8192;
#pragma unroll
      for (int i = 0; i < 8; ++i) {
        int chunk = i * 2 + w;
        gll16(g + chunk * 512 + lane * 8, dst + chunk * 512);
      }
    };
    auto computeB = [&](const unsigned short* buf) {
#pragma unroll
      for (int tc = 0; tc < 4; ++tc) {
        bf16x8 bfr[4];
#pragma unroll
        for (int ks = 0; ks < 4; ++ks)
          bfr[ks] = *reinterpret_cast<const bf16x8*>(buf + (tc * 4 + ks) * 512 +
                                                     lane * 8);
#pragma unroll
        for (int tr = 0; tr < 4; ++tr) {
          f32x4 acc = {0.f, 0.f, 0.f, 0.f};
#pragma unroll
          for (int ks = 0; ks < 4; ++ks)
            acc = __builtin_amdgcn_mfma_f32_16x16x32_bf16(afrag[tr][ks],
                                                          bfr[ks], acc, 0, 0, 0);
          // C/D layout (verified): col = lane&15, row = quad*4 + r
#pragma unroll
          for (int r = 0; r < 4; ++r) all_p[tr * 4 + r] += fast_exp2(acc[r]);
        }
      }
    };

    const int cbase = cs * CPS;
    stage(lds0, cbase);
    __syncthreads(); // tile 0 resident
    for (int ct = 0; ct < NCT; ct += 2) {
      if (ct + 1 < NCT) stage(lds1, cbase + (ct + 1) * BN);
      computeB(lds0);
      __syncthreads(); // drains vmcnt(0): lds1 staged; all done reading lds0
      if (ct + 2 < NCT) stage(lds0, cbase + (ct + 2) * BN);
      computeB(lds1);
      __syncthreads();
    }

#pragma unroll
    for (int t = 0; t < 16; ++t) {
      float a = all_p[t];
#pragma unroll
      for (int m = 8; m >= 1; m >>= 1) a += __shfl_xor(a, m, 64);
      if (col16 == 0) {
        int row_g = r0 + w * 64 + (t >> 2) * 16 + quad * 4 + (t & 3);
        ws_all[cs * N_EMB + row_g] = a;
      }
    }
  } else {
    // ------------------------- pos-path -------------------------
    const int l = blockIdx.x >> 1;                       // 0..63
    const int chunk = (cs - NSPLIT) * 2 + (blockIdx.x & 1); // 0..7
    const int gs = gstart[l], ge = gstart[l + 1];
    const int t0 = gs >> 4;
    const int t1 = (ge + 15) >> 4;

    for (int ta = t0 + chunk * 2 + w; ta < t1; ta += 16) {
      bf16x8 af[4];
      const unsigned short* pa = eraw + (size_t)(ta >> 3) * (128 * DIM) +
                                 ((ta & 7) * 4) * 512 + lane * 8;
#pragma unroll
      for (int ks = 0; ks < 4; ++ks) af[ks] = load_scaled(pa + ks * 512);
      const int grow = ta * 16 + quad * 4; // this lane's 4 rows: grow+r
      float posr[4] = {0.f, 0.f, 0.f, 0.f};

      for (int tb = t0; tb < t1; ++tb) {
        bf16x8 bfr[4];
        const unsigned short* pb = eraw + (size_t)(tb >> 3) * (128 * DIM) +
                                   ((tb & 7) * 4) * 512 + lane * 8;
#pragma unroll
        for (int ks = 0; ks < 4; ++ks)
          bfr[ks] = *reinterpret_cast<const bf16x8*>(pb + ks * 512);
        f32x4 acc = {0.f, 0.f, 0.f, 0.f};
#pragma unroll
        for (int ks = 0; ks < 4; ++ks)
          acc = __builtin_amdgcn_mfma_f32_16x16x32_bf16(af[ks], bfr[ks], acc,
                                                        0, 0, 0);
        const int gcol = tb * 16 + col16;
        const bool colin = (gcol >= gs) && (gcol < ge);
#pragma unroll
        for (int r = 0; r < 4; ++r) {
          float e = fast_exp2(acc[r]);
          const int gr = grow + r;
          if (gcol == gr) {
            if (colin) ws_diag[gr] = e; // exactly one writer per row
          } else if (colin) {
            posr[r] += e;
          }
        }
      }

#pragma unroll
      for (int r = 0; r < 4; ++r) {
        float p = posr[r];
#pragma unroll
        for (int m = 8; m >= 1; m >>= 1) p += __shfl_xor(p, m, 64);
        const int gr = grow + r;
        if (col16 == 0 && gr >= gs && gr < ge) ws_pos[gr] = p;
      }
    }
  }
}

// ---------------------------------------------------------------------------
// Finalize: 64-block partial reduce, then one wave combines.
// ---------------------------------------------------------------------------
__global__ __launch_bounds__(256) void fin1(
    const float* __restrict__ ws_all, const float* __restrict__ ws_pos,
    const float* __restrict__ ws_diag, float* __restrict__ part_tot,
    int* __restrict__ part_cnt) {
  __shared__ float s_t[256];
  __shared__ int s_c[256];
  const int tid = threadIdx.x;
  const int row = blockIdx.x * 256 + tid;
  float a = 0.f;
#pragma unroll
  for (int s = 0; s < NSPLIT; ++s) a += ws_all[s * N_EMB + row];
  a -= ws_diag[row];
  const float p = ws_pos[row];
  float t = 0.f;
  int c = 0;
  if (p > 0.f) {
    t = fast_log2(a) - fast_log2(p);
    c = 1;
  }
  s_t[tid] = t;
  s_c[tid] = c;
  __syncthreads();
  for (int s = 128; s > 0; s >>= 1) {
    if (tid < s) {
      s_t[tid] += s_t[tid + s];
      s_c[tid] += s_c[tid + s];
    }
    __syncthreads();
  }
  if (tid == 0) {
    part_tot[blockIdx.x] = s_t[0];
    part_cnt[blockIdx.x] = s_c[0];
  }
}

__global__ __launch_bounds__(64) void fin2(const float* __restrict__ part_tot,
                                           const int* __restrict__ part_cnt,
                                           float* __restrict__ out) {
  const int tid = threadIdx.x;
  float t = part_tot[tid];
  int c = part_cnt[tid];
#pragma unroll
  for (int m = 32; m >= 1; m >>= 1) {
    t += __shfl_xor(t, m, 64);
    c += __shfl_xor(c, m, 64);
  }
  if (tid == 0) out[0] = (c > 0) ? (t * LN2 / (float)c) : 0.f;
}

extern "C" void kernel_launch(void* const* d_in, const int* in_sizes, int n_in,
                              void* d_out, int out_size, void* d_ws,
                              size_t ws_size, hipStream_t stream) {
  const float* emb = (const float*)d_in[0];
  const int* labels = (const int*)d_in[1];

  unsigned short* eraw = (unsigned short*)d_ws;         // 4 MB bf16 frag-linear
  float* ws_all = (float*)(eraw + (size_t)N_EMB * DIM); // [NSPLIT][N] 1 MB
  float* ws_pos = ws_all + NSPLIT * N_EMB;              // [N] 64 KB
  float* ws_diag = ws_pos + N_EMB;                      // [N] 64 KB
  float* part_tot = ws_diag + N_EMB;                    // [64]
  int* part_cnt = (int*)(part_tot + 64);                // [64]
  int* perm = part_cnt + 64;                            // [N] 64 KB
  int* gstart = perm + N_EMB;                           // [65]

  perm_kernel<<<1, 1024, 0, stream>>>(labels, perm, gstart);
  preconv<<<512, 256, 0, stream>>>(emb, perm, eraw);
  cl_fused<<<dim3(128, NSPLIT + POSY), 128, 0, stream>>>(eraw, gstart, ws_all,
                                                         ws_pos, ws_diag);
  fin1<<<N_EMB / 256, 256, 0, stream>>>(ws_all, ws_pos, ws_diag, part_tot,
                                        part_cnt);
  fin2<<<1, 64, 0, stream>>>(part_tot, part_cnt, (float*)d_out);
}